// Round 9
// baseline (137.030 us; speedup 1.0000x reference)
//
#include <hip/hip_runtime.h>

// DCNv2, fp32 in/out, fused MFMA path, MAX-MLP variant:
// all scattered gathers per phase are issued in one batch (sched_barrier(0)
// fence) so ~36 loads are in flight per wave before any blend/MFMA consumes.
// Block = 4 waves = 2 px-tiles x 2 kc-halves (R8 skeleton).
// B-frag: n=lane&15, k=(lane>>4)*8+j (K=32).  D: col=lane&15, row=(lane>>4)*4+reg.
// ws: xT 8388608 B | wdA 73728 B | woAhi 36864 B | woAlo 36864 B

#define BATCH 4
#define CIN   64
#define COUT  64
#define HH    128
#define WW    128
#define HWPIX (HH*WW)

typedef __attribute__((ext_vector_type(8))) short short8;   // 8 bf16 (4 VGPRs)
typedef __attribute__((ext_vector_type(4))) float floatx4;  // MFMA C/D

__device__ __forceinline__ unsigned short f2bf(float f) {   // RNE f32->bf16
  unsigned int u = __float_as_uint(f);
  unsigned int r = u + 0x7fffu + ((u >> 16) & 1u);
  return (unsigned short)(r >> 16);
}
__device__ __forceinline__ float bf2f(unsigned short h) { return __uint_as_float(((unsigned int)h) << 16); }
__device__ __forceinline__ float lo16f(unsigned int u) { return __uint_as_float(u << 16); }
__device__ __forceinline__ float hi16f(unsigned int u) { return __uint_as_float(u & 0xffff0000u); }

__device__ __forceinline__ unsigned int bilin2(unsigned int u00, unsigned int u01,
                                               unsigned int u10, unsigned int u11,
                                               float w00, float w01, float w10, float w11) {
  float lo = w00 * lo16f(u00) + w01 * lo16f(u01) + w10 * lo16f(u10) + w11 * lo16f(u11);
  float hi = w00 * hi16f(u00) + w01 * hi16f(u01) + w10 * hi16f(u10) + w11 * hi16f(u11);
  return (unsigned int)f2bf(lo) | ((unsigned int)f2bf(hi) << 16);
}

// x fp32 NCHW -> xT bf16 [b][px][cin]
__global__ __launch_bounds__(256) void transpose_x_kernel(const float* __restrict__ x,
                                                          unsigned short* __restrict__ xT) {
  __shared__ float tile[32][33];   // [c_local][p_local]
  int b = blockIdx.z, p0 = blockIdx.x * 32, c0 = blockIdx.y * 32;
  int tx = threadIdx.x, ty = threadIdx.y;        // (32,8)
  const float* xb = x + (size_t)b * CIN * HWPIX;
  unsigned short* xTb = xT + (size_t)b * HWPIX * CIN;
#pragma unroll
  for (int i = 0; i < 4; i++)
    tile[ty + i * 8][tx] = xb[(size_t)(c0 + ty + i * 8) * HWPIX + p0 + tx];
  __syncthreads();
  int wid = ty * 32 + tx;          // 0..255 = 32 rows x 8 cin-quads
  int row = wid >> 3, q = wid & 7;
  ushort4 v = make_ushort4(f2bf(tile[q * 4 + 0][row]), f2bf(tile[q * 4 + 1][row]),
                           f2bf(tile[q * 4 + 2][row]), f2bf(tile[q * 4 + 3][row]));
  *(ushort4*)&xTb[(size_t)(p0 + row) * CIN + c0 + q * 4] = v;
}

// wdA[kk][kc2][ct4][lane][j] bf16 (36864 entries);
// woAhi/lo[kk][kc2][ct2][lane][j] bf16 (M=32 rows, rows>=18 zero; 18432 each)
__global__ __launch_bounds__(256) void prep_weights_kernel(const float* __restrict__ wo,
                                                           const float* __restrict__ wd,
                                                           unsigned short* __restrict__ wdA,
                                                           unsigned short* __restrict__ woAhi,
                                                           unsigned short* __restrict__ woAlo) {
  int t = blockIdx.x * 256 + threadIdx.x;
  if (t < 36864) {
    int j = t & 7, lane = (t >> 3) & 63, ct = (t >> 9) & 3, kc = (t >> 11) & 1, kk = t >> 12;
    int cout = ct * 16 + (lane & 15);
    int cin  = kc * 32 + (lane >> 4) * 8 + j;
    wdA[t] = f2bf(wd[(size_t)(cout * CIN + cin) * 9 + kk]);
  }
  int t2 = t - 36864;
  if (t2 >= 0 && t2 < 18432) {
    int j = t2 & 7, lane = (t2 >> 3) & 63, ct = (t2 >> 9) & 1, kc = (t2 >> 10) & 1, kk = t2 >> 11;
    int cout = ct * 16 + (lane & 15);          // conv channel 0..31 (valid < 18)
    int cin  = kc * 32 + (lane >> 4) * 8 + j;
    float v = (cout < 18) ? wo[(size_t)(cout * CIN + cin) * 9 + kk] : 0.f;
    unsigned short h = f2bf(v);
    woAhi[t2] = h;
    woAlo[t2] = f2bf(v - bf2f(h));
  }
}

// Fused offset-conv + deform, batched-gather max-MLP version.
__global__ __launch_bounds__(256, 2) void fused_dcn_kernel(const unsigned short* __restrict__ xT,
                                                           const unsigned short* __restrict__ wdA,
                                                           const unsigned short* __restrict__ woAhi,
                                                           const unsigned short* __restrict__ woAlo,
                                                           float* __restrict__ out) {
  __shared__ float shmem[2048];        // 8 KB: offsP (1152 f) then redL (2048 f)
  float* offsP = shmem;
  float* redL  = shmem;

  int tid = threadIdx.x;
  int lane = tid & 63, w = tid >> 6;
  int t = w >> 1, kc = w & 1;          // px-tile, cin-half
  int hw = blockIdx.x;                 // 2048 blocks
  int bid = (hw & 7) * 256 + (hw >> 3);  // XCD-contiguous bands
  int b = bid >> 9, r = bid & 511, y = r >> 2, x0 = (r & 3) << 5;

  int pxl = lane & 15, kq = lane >> 4;
  int px  = x0 + t * 16 + pxl;
  int klo = kc * 32 + kq * 8;
  int rowb = kq * 4;

  const unsigned short* xTb = xT + (size_t)b * HWPIX * CIN;
  const short8 zero8 = {0, 0, 0, 0, 0, 0, 0, 0};

  // ---------- phase A: offset conv partial, batched gathers ----------
  {
    short8 bA[9];
    unsigned int avm = 0;
#pragma unroll
    for (int kk = 0; kk < 9; kk++) {
      int ys = y - 1 + kk / 3;
      int xs = px - 1 + kk % 3;
      bool valid = ((unsigned)ys < (unsigned)HH) && ((unsigned)xs < (unsigned)WW);
      int yc = min(max(ys, 0), HH - 1), xc = min(max(xs, 0), WW - 1);
      bA[kk] = *(const short8*)(xTb + (size_t)(yc * WW + xc) * CIN + klo);
      if (valid) avm |= (1u << kk);
    }
    __builtin_amdgcn_sched_barrier(0);   // all 9 loads issued before any use

    floatx4 oacc[2];
    oacc[0] = (floatx4){0.f, 0.f, 0.f, 0.f};
    oacc[1] = (floatx4){0.f, 0.f, 0.f, 0.f};
#pragma unroll
    for (int kk = 0; kk < 9; kk++) {
      short8 b0 = bA[kk];
      if (!(avm & (1u << kk))) b0 = zero8;
      const short8* Ah = (const short8*)(woAhi + (size_t)kk * 2048 + kc * 1024);
      const short8* Al = (const short8*)(woAlo + (size_t)kk * 2048 + kc * 1024);
#pragma unroll
      for (int ct = 0; ct < 2; ct++) {
        oacc[ct] = __builtin_amdgcn_mfma_f32_16x16x32_bf16(Ah[ct * 64 + lane], b0, oacc[ct], 0, 0, 0);
        oacc[ct] = __builtin_amdgcn_mfma_f32_16x16x32_bf16(Al[ct * 64 + lane], b0, oacc[ct], 0, 0, 0);
      }
    }
#pragma unroll
    for (int ct = 0; ct < 2; ct++)
#pragma unroll
      for (int rr = 0; rr < 4; rr++) {
        int row = ct * 16 + rowb + rr;
        if (row < 18) offsP[(w * 18 + row) * 16 + pxl] = oacc[ct][rr];
      }
  }
  __syncthreads();

  // ---------- phase B: precompute all positions, batch all 36 gathers ----------
  int  pk[9];       // packed: p00 | dxc<<14 | dyc<<15
  float4 cw[9];     // corner weights
#pragma unroll
  for (int kk = 0; kk < 9; kk++) {
    float dy = offsP[((2 * t) * 18 + 2 * kk) * 16 + pxl] +
               offsP[((2 * t + 1) * 18 + 2 * kk) * 16 + pxl];
    float dx = offsP[((2 * t) * 18 + 2 * kk + 1) * 16 + pxl] +
               offsP[((2 * t + 1) * 18 + 2 * kk + 1) * 16 + pxl];
    float ysf = (float)(y - 1 + kk / 3) + dy;
    float xsf = (float)(px - 1 + kk % 3) + dx;
    float y0f = floorf(ysf), x0f = floorf(xsf);
    float wy = ysf - y0f, wx = xsf - x0f;
    int iy0 = (int)y0f, ix0 = (int)x0f;
    int iy1 = iy0 + 1, ix1 = ix0 + 1;
    float w00 = (1.f - wy) * (1.f - wx), w01 = (1.f - wy) * wx;
    float w10 = wy * (1.f - wx), w11 = wy * wx;
    bool vy0 = ((unsigned)iy0 < (unsigned)HH), vy1 = ((unsigned)iy1 < (unsigned)HH);
    bool vx0 = ((unsigned)ix0 < (unsigned)WW), vx1 = ((unsigned)ix1 < (unsigned)WW);
    if (!(vy0 && vx0)) w00 = 0.f;
    if (!(vy0 && vx1)) w01 = 0.f;
    if (!(vy1 && vx0)) w10 = 0.f;
    if (!(vy1 && vx1)) w11 = 0.f;
    cw[kk] = make_float4(w00, w01, w10, w11);
    int cy0 = min(max(iy0, 0), HH - 1), cy1 = min(max(iy1, 0), HH - 1);
    int cx0 = min(max(ix0, 0), WW - 1), cx1 = min(max(ix1, 0), WW - 1);
    pk[kk] = (cy0 * WW + cx0) | ((cx1 - cx0) << 14) | ((cy1 - cy0) << 15);
  }

  uint4 g00[9], g01[9], g10[9], g11[9];
  const unsigned short* bp = xTb + klo;
#pragma unroll
  for (int kk = 0; kk < 9; kk++) {
    int p00 = pk[kk] & 0x3FFF;
    int dxc = (pk[kk] >> 14) & 1;
    int dyc = ((pk[kk] >> 15) & 1) * WW;
    g00[kk] = *(const uint4*)(bp + (size_t)p00 * CIN);
    g01[kk] = *(const uint4*)(bp + (size_t)(p00 + dxc) * CIN);
    g10[kk] = *(const uint4*)(bp + (size_t)(p00 + dyc) * CIN);
    g11[kk] = *(const uint4*)(bp + (size_t)(p00 + dyc + dxc) * CIN);
  }
  __builtin_amdgcn_sched_barrier(0);   // all 36 gathers in flight before blends

  floatx4 acc[4];
#pragma unroll
  for (int ct = 0; ct < 4; ct++) acc[ct] = (floatx4){0.f, 0.f, 0.f, 0.f};

#pragma unroll
  for (int kk = 0; kk < 9; kk++) {
    float4 wv = cw[kk];
    uint4 u;
    u.x = bilin2(g00[kk].x, g01[kk].x, g10[kk].x, g11[kk].x, wv.x, wv.y, wv.z, wv.w);
    u.y = bilin2(g00[kk].y, g01[kk].y, g10[kk].y, g11[kk].y, wv.x, wv.y, wv.z, wv.w);
    u.z = bilin2(g00[kk].z, g01[kk].z, g10[kk].z, g11[kk].z, wv.x, wv.y, wv.z, wv.w);
    u.w = bilin2(g00[kk].w, g01[kk].w, g10[kk].w, g11[kk].w, wv.x, wv.y, wv.z, wv.w);
    short8 bv = *(short8*)&u;
    const short8* Ap = (const short8*)(wdA + (size_t)kk * 4096 + kc * 2048);
#pragma unroll
    for (int ct = 0; ct < 4; ct++)
      acc[ct] = __builtin_amdgcn_mfma_f32_16x16x32_bf16(Ap[ct * 64 + lane], bv, acc[ct], 0, 0, 0);
  }

  // ---------- cross-kc reduce + store ----------
  __syncthreads();                     // offsP dead; reuse shmem as redL
  if (kc == 1) {
#pragma unroll
    for (int ct = 0; ct < 4; ct++)
#pragma unroll
      for (int rr = 0; rr < 4; rr++)
        redL[((t * 4 + ct) * 4 + rr) * 64 + lane] = acc[ct][rr];
  }
  __syncthreads();
  if (kc == 0) {
    float* outb = out + (size_t)b * COUT * HWPIX + y * WW + px;
#pragma unroll
    for (int ct = 0; ct < 4; ct++)
#pragma unroll
      for (int rr = 0; rr < 4; rr++) {
        float v = acc[ct][rr] + redL[((t * 4 + ct) * 4 + rr) * 64 + lane];
        outb[(size_t)(ct * 16 + rowb + rr) * HWPIX] = v;
      }
  }
}

extern "C" void kernel_launch(void* const* d_in, const int* in_sizes, int n_in,
                              void* d_out, int out_size, void* d_ws, size_t ws_size,
                              hipStream_t stream) {
  const float* x  = (const float*)d_in[0];
  const float* wo = (const float*)d_in[1];
  const float* wd = (const float*)d_in[2];
  float* out = (float*)d_out;

  char* wsb = (char*)d_ws;
  unsigned short* xT    = (unsigned short*)wsb;                      // 8,388,608 B
  unsigned short* wdA   = (unsigned short*)(wsb + 8388608);          // 73,728 B
  unsigned short* woAhi = (unsigned short*)(wsb + 8388608 + 73728);  // 36,864 B
  unsigned short* woAlo = (unsigned short*)(wsb + 8388608 + 110592); // 36,864 B

  transpose_x_kernel<<<dim3(HWPIX / 32, CIN / 32, BATCH), dim3(32, 8, 1), 0, stream>>>(x, xT);
  prep_weights_kernel<<<dim3(216), dim3(256), 0, stream>>>(wo, wd, wdA, woAhi, woAlo);
  fused_dcn_kernel<<<dim3(BATCH * HWPIX / 32), dim3(256), 0, stream>>>(xT, wdA, woAhi, woAlo, out);
}